// Round 18
// baseline (131.778 us; speedup 1.0000x reference)
//
#include <hip/hip_runtime.h>

typedef unsigned short u16;
typedef unsigned int   u32;
typedef __attribute__((ext_vector_type(2)))  unsigned u32x2;
typedef __attribute__((ext_vector_type(4)))  float  f32x4;
typedef __attribute__((ext_vector_type(8)))  short  s16x8;

__device__ __forceinline__ u16 f2bf(float f) {
  unsigned u = __builtin_bit_cast(unsigned, f);
  u += 0x7FFFu + ((u >> 16) & 1u);
  return (u16)(u >> 16);
}

__device__ __forceinline__ float exp2g(float x) { return __builtin_amdgcn_exp2f(x); }

__device__ __forceinline__ void gload16(const void* g, void* l) {
  __builtin_amdgcn_global_load_lds(
      (const __attribute__((address_space(1))) void*)g,
      (__attribute__((address_space(3))) void*)l, 16, 0, 0);
}

// ---------------- LayerNorm (fp32 in -> bf16 out) ----------------
__global__ __launch_bounds__(256) void ln_kernel(
    const float* __restrict__ x, const float* __restrict__ gamma,
    const float* __restrict__ beta, u16* __restrict__ xn)
{
  const int row = blockIdx.x, tid = threadIdx.x;
  const float* xr = x + (size_t)row * 1024;
  float4 v = *(const float4*)(xr + tid * 4);
  float s  = v.x + v.y + v.z + v.w;
  float s2 = v.x*v.x + v.y*v.y + v.z*v.z + v.w*v.w;
#pragma unroll
  for (int off = 32; off >= 1; off >>= 1) {
    s  += __shfl_xor(s,  off);
    s2 += __shfl_xor(s2, off);
  }
  __shared__ float red[8];
  const int w = tid >> 6, l = tid & 63;
  if (l == 0) { red[w] = s; red[w + 4] = s2; }
  __syncthreads();
  s  = red[0] + red[1] + red[2] + red[3];
  s2 = red[4] + red[5] + red[6] + red[7];
  const float mu  = s * (1.0f / 1024.0f);
  const float var = s2 * (1.0f / 1024.0f) - mu * mu;
  const float rs  = rsqrtf(var + 1e-5f);
  float4 g  = *(const float4*)(gamma + tid * 4);
  float4 be = *(const float4*)(beta  + tid * 4);
  ushort4 o;
  o.x = f2bf((v.x - mu) * rs * g.x + be.x);
  o.y = f2bf((v.y - mu) * rs * g.y + be.y);
  o.z = f2bf((v.z - mu) * rs * g.z + be.z);
  o.w = f2bf((v.w - mu) * rs * g.w + be.w);
  *(ushort4*)(xn + (size_t)row * 1024 + tid * 4) = o;
}

// ---------------- transpose + fp32->bf16 convert ----------------
__global__ void transpose_cvt(const float* __restrict__ in, u16* __restrict__ out,
                              int R, int C)
{
  __shared__ float t[32][33];
  const int bc = blockIdx.x * 32, br = blockIdx.y * 32;
  const int x = threadIdx.x;
#pragma unroll
  for (int i = threadIdx.y; i < 32; i += 8)
    t[i][x] = in[(size_t)(br + i) * C + bc + x];
  __syncthreads();
#pragma unroll
  for (int i = threadIdx.y; i < 32; i += 8)
    out[(size_t)(bc + i) * R + br + x] = f2bf(t[x][i]);
}

// ---------------- GEMM 128x128, counted-vmcnt pipeline (r17-verified) ----------------
__device__ __forceinline__ void store_out(float* p, float v) { *p = v; }
__device__ __forceinline__ void store_out(u16* p, float v)   { *p = f2bf(v); }

template <typename OutT>
__global__ __launch_bounds__(256) void gemm_bt(
    const u16* __restrict__ A, const u16* __restrict__ Bt,
    const float* __restrict__ bias, OutT* __restrict__ C,
    int M, int N, int K)
{
  __shared__ u16 As[2][128 * 32];
  __shared__ u16 Bs[2][128 * 32];
  const int tid = threadIdx.x;
  const int w = tid >> 6, l = tid & 63;
  const int g = l >> 4, li = l & 15;
  const int bm = blockIdx.y * 128, bn = blockIdx.x * 128;
  const int wr = (w >> 1) * 64, wc = (w & 1) * 64;

  f32x4 acc[4][4] = {};

  const int ar0 = tid >> 2,          as0 = tid & 3;
  const int ar1 = (tid + 256) >> 2,  as1 = (tid + 256) & 3;
  const u16* pa0 = A  + (size_t)(bm + ar0) * K + 8 * (as0 ^ (ar0 & 3));
  const u16* pa1 = A  + (size_t)(bm + ar1) * K + 8 * (as1 ^ (ar1 & 3));
  const u16* pb0 = Bt + (size_t)(bn + ar0) * K + 8 * (as0 ^ (ar0 & 3));
  const u16* pb1 = Bt + (size_t)(bn + ar1) * K + 8 * (as1 ^ (ar1 & 3));

  auto stage = [&](int b, int kt) {
    gload16(pa0 + kt, &As[b][w * 512]);
    gload16(pa1 + kt, &As[b][2048 + w * 512]);
    gload16(pb0 + kt, &Bs[b][w * 512]);
    gload16(pb1 + kt, &Bs[b][2048 + w * 512]);
  };

  stage(0, 0);
  if (K > 32) stage(1, 32);

  int buf = 0;
  for (int kt = 0; kt < K; kt += 32) {
    if (kt + 32 < K) asm volatile("s_waitcnt vmcnt(4)" ::: "memory");
    else             asm volatile("s_waitcnt vmcnt(0)" ::: "memory");
    __builtin_amdgcn_s_barrier();

    const u16* as = &As[buf][0];
    const u16* bs = &Bs[buf][0];

    s16x8 af[4], bf[4];
#pragma unroll
    for (int m = 0; m < 4; ++m) {
      const int row = wr + m * 16 + li;
      af[m] = *(const s16x8*)(as + row * 32 + 8 * (g ^ (row & 3)));
    }
#pragma unroll
    for (int n = 0; n < 4; ++n) {
      const int row = wc + n * 16 + li;
      bf[n] = *(const s16x8*)(bs + row * 32 + 8 * (g ^ (row & 3)));
    }
    __builtin_amdgcn_s_setprio(1);
#pragma unroll
    for (int m = 0; m < 4; ++m)
#pragma unroll
      for (int n = 0; n < 4; ++n)
        acc[m][n] = __builtin_amdgcn_mfma_f32_16x16x32_bf16(af[m], bf[n], acc[m][n], 0, 0, 0);
    __builtin_amdgcn_s_setprio(0);

    __builtin_amdgcn_s_barrier();
    if (kt + 64 < K) stage(buf, kt + 64);
    buf ^= 1;
  }

#pragma unroll
  for (int n = 0; n < 4; ++n) {
    const int col = bn + wc + n * 16 + li;
    const float bv = bias[col];
#pragma unroll
    for (int m = 0; m < 4; ++m) {
      const int row0 = bm + wr + m * 16 + g * 4;
#pragma unroll
      for (int r = 0; r < 4; ++r)
        store_out(C + (size_t)(row0 + r) * N + col, acc[m][n][r] + bv);
    }
  }
}

// ---------------- GEMM 64x128 (occupancy variant), counted-vmcnt (r17-verified) ----------------
template <typename OutT>
__global__ __launch_bounds__(256) void gemm_bt64(
    const u16* __restrict__ A, const u16* __restrict__ Bt,
    const float* __restrict__ bias, OutT* __restrict__ C,
    int M, int N, int K)
{
  __shared__ u16 As[2][64 * 32];
  __shared__ u16 Bs[2][128 * 32];
  const int tid = threadIdx.x;
  const int w = tid >> 6, l = tid & 63;
  const int g = l >> 4, li = l & 15;
  const int bm = blockIdx.y * 64, bn = blockIdx.x * 128;
  const int wr = (w >> 1) * 32, wc = (w & 1) * 64;

  f32x4 acc[2][4] = {};

  const int ar = tid >> 2,           asl = tid & 3;
  const int br0 = tid >> 2,          bs0 = tid & 3;
  const int br1 = (tid + 256) >> 2,  bs1 = (tid + 256) & 3;
  const u16* pa  = A  + (size_t)(bm + ar)  * K + 8 * (asl ^ (ar  & 3));
  const u16* pb0 = Bt + (size_t)(bn + br0) * K + 8 * (bs0 ^ (br0 & 3));
  const u16* pb1 = Bt + (size_t)(bn + br1) * K + 8 * (bs1 ^ (br1 & 3));

  auto stage = [&](int b, int kt) {
    gload16(pa  + kt, &As[b][w * 512]);
    gload16(pb0 + kt, &Bs[b][w * 512]);
    gload16(pb1 + kt, &Bs[b][2048 + w * 512]);
  };

  stage(0, 0);
  if (K > 32) stage(1, 32);

  int buf = 0;
  for (int kt = 0; kt < K; kt += 32) {
    if (kt + 32 < K) asm volatile("s_waitcnt vmcnt(3)" ::: "memory");
    else             asm volatile("s_waitcnt vmcnt(0)" ::: "memory");
    __builtin_amdgcn_s_barrier();

    const u16* as = &As[buf][0];
    const u16* bs = &Bs[buf][0];

    s16x8 af[2], bf[4];
#pragma unroll
    for (int m = 0; m < 2; ++m) {
      const int row = wr + m * 16 + li;
      af[m] = *(const s16x8*)(as + row * 32 + 8 * (g ^ (row & 3)));
    }
#pragma unroll
    for (int n = 0; n < 4; ++n) {
      const int row = wc + n * 16 + li;
      bf[n] = *(const s16x8*)(bs + row * 32 + 8 * (g ^ (row & 3)));
    }
    __builtin_amdgcn_s_setprio(1);
#pragma unroll
    for (int m = 0; m < 2; ++m)
#pragma unroll
      for (int n = 0; n < 4; ++n)
        acc[m][n] = __builtin_amdgcn_mfma_f32_16x16x32_bf16(af[m], bf[n], acc[m][n], 0, 0, 0);
    __builtin_amdgcn_s_setprio(0);

    __builtin_amdgcn_s_barrier();
    if (kt + 64 < K) stage(buf, kt + 64);
    buf ^= 1;
  }

#pragma unroll
  for (int n = 0; n < 4; ++n) {
    const int col = bn + wc + n * 16 + li;
    const float bv = bias[col];
#pragma unroll
    for (int m = 0; m < 2; ++m) {
      const int row0 = bm + wr + m * 16 + g * 4;
#pragma unroll
      for (int r = 0; r < 4; ++r)
        store_out(C + (size_t)(row0 + r) * N + col, acc[m][n][r] + bv);
    }
  }
}

// ---------------- flash attention: 2 q-blocks/wave, shared K/V frags ----------------
// qkv: [4096][3072] bf16; out: [4096][1024] bf16
// grid 512 (16 qt x 16 h x 2 b); block = 4 waves; wave owns 32 q-rows (A: li, B: li+16).
__global__ __launch_bounds__(256, 2) void attn_kernel(
    const u16* __restrict__ qkv, u16* __restrict__ outp)
{
  __shared__ u16 Ks[2][4096];   // [kv][d] dbuf, 16B chunks XOR-swizzled by (kv&7)  (verified)
  __shared__ u16 Vt[4096];      // [d][kv] single, byte XOR ((d^(d>>3))&7)<<4       (verified)
  __shared__ u16 Pl[4 * 2048];  // per-wave 4KB: P_A[q=li][64kv] | P_B, XOR ((li&7)<<4)

  const int tid = threadIdx.x;
  const int w = tid >> 6, l = tid & 63;
  const int g = l >> 4, li = l & 15;

  // T1: bijective XCD swizzle (512 = 8 * 64)
  const int lb = (blockIdx.x & 7) * 64 + (blockIdx.x >> 3);
  const int qt = lb & 15;
  const int h  = (lb >> 4) & 15;
  const int bb = lb >> 8;
  const size_t baserow = (size_t)bb * 2048;

  // Q fragments for both 16-row blocks (B-operands; r13-verified pattern)
  const int qbase = qt * 128 + w * 32;
  const u16* qpA = qkv + (baserow + qbase + li) * 3072 + h * 64 + 8 * g;
  const u16* qpB = qpA + (size_t)16 * 3072;
  const s16x8 qfA0 = *(const s16x8*)(qpA);
  const s16x8 qfA1 = *(const s16x8*)(qpA + 32);
  const s16x8 qfB0 = *(const s16x8*)(qpB);
  const s16x8 qfB1 = *(const s16x8*)(qpB + 32);

  // K staging (verified): chunk c -> kv c>>3, slot c&7, pre-swizzled source
  const int kr0 = tid >> 3,         kc0 = tid & 7;
  const int kr1 = (tid + 256) >> 3, kc1 = (tid + 256) & 7;
  const u16* kg0 = qkv + (baserow + kr0) * 3072 + 1024 + h * 64 + 8 * (kc0 ^ (kr0 & 7));
  const u16* kg1 = qkv + (baserow + kr1) * 3072 + 1024 + h * 64 + 8 * (kc1 ^ (kr1 & 7));

  // V reg-staging: thread owns kv-pair vp x d-group dg
  const int vp = tid >> 3, dg = tid & 7;
  const u16* vgA = qkv + (baserow + 2 * vp)     * 3072 + 2048 + h * 64 + 8 * dg;
  const u16* vgB = qkv + (baserow + 2 * vp + 1) * 3072 + 2048 + h * 64 + 8 * dg;

  auto issueK = [&](int b, int t) {
    const size_t koff = (size_t)t * (64 * 3072);
    gload16(kg0 + koff, &Ks[b][w * 512]);
    gload16(kg1 + koff, &Ks[b][2048 + w * 512]);
  };

  const float C1  = 0.18033688f;   // 0.125 * log2(e)
  const float THR = 11.5416f;      // 8 * log2(e)
  float MA = -1e30f, MB = -1e30f;
  f32x4 oA[4] = {}, oB[4] = {}, osA = {}, osB = {};

  s16x8 ones;
#pragma unroll
  for (int j = 0; j < 8; ++j) ones[j] = (short)0x3F80;   // bf16 1.0

  char* PwA = (char*)(Pl + w * 2048);   // 2KB region
  char* PwB = PwA + 2048;               // 2KB region
  const int pswz = (li & 7) << 4;

  // prologue: prefetch tile 0
  issueK(0, 0);
  s16x8 va = *(const s16x8*)vgA;
  s16x8 vb = *(const s16x8*)vgB;

  int buf = 0;
  for (int t = 0; t < 32; ++t) {
    // V regs (tile t) -> Vt; paired-kv b32 writes, verified swizzle involution
#pragma unroll
    for (int j = 0; j < 8; ++j) {
      const int d = 8 * dg + j;
      const u32 val = (u32)(u16)va[j] | ((u32)(u16)vb[j] << 16);
      *(u32*)((char*)Vt + d * 128 + ((4 * vp) ^ ((((d ^ (d >> 3)) & 7)) << 4))) = val;
    }
    __syncthreads();   // K[buf] gload drained; Vt visible

    if (t < 31) {      // prefetch next tile
      issueK(buf ^ 1, t + 1);
      const size_t koff = (size_t)(t + 1) * (64 * 3072);
      va = *(const s16x8*)(vgA + koff);
      vb = *(const s16x8*)(vgB + koff);
    }

    const u16* kb = &Ks[buf][0];

    // ---- S^T = K . Q^T for both q-blocks; 8 kf reads serve 16 MFMA ----
    f32x4 sA[4] = {}, sB[4] = {};
    __builtin_amdgcn_s_setprio(1);
#pragma unroll
    for (int nk = 0; nk < 4; ++nk) {
      const int kvr = nk * 16 + li;
      const s16x8 kf0 = *(const s16x8*)((const char*)kb + kvr * 128 + 16 * ((0 + g) ^ (kvr & 7)));
      const s16x8 kf1 = *(const s16x8*)((const char*)kb + kvr * 128 + 16 * ((4 + g) ^ (kvr & 7)));
      sA[nk] = __builtin_amdgcn_mfma_f32_16x16x32_bf16(kf0, qfA0, sA[nk], 0, 0, 0);
      sA[nk] = __builtin_amdgcn_mfma_f32_16x16x32_bf16(kf1, qfA1, sA[nk], 0, 0, 0);
      sB[nk] = __builtin_amdgcn_mfma_f32_16x16x32_bf16(kf0, qfB0, sB[nk], 0, 0, 0);
      sB[nk] = __builtin_amdgcn_mfma_f32_16x16x32_bf16(kf1, qfB1, sB[nk], 0, 0, 0);
    }
    __builtin_amdgcn_s_setprio(0);

    // ---- softmax: lane-local max + 2 shuffles, per q-block ----
    float lmA = fmaxf(fmaxf(sA[0][0], sA[0][1]), fmaxf(sA[0][2], sA[0][3]));
    float lmB = fmaxf(fmaxf(sB[0][0], sB[0][1]), fmaxf(sB[0][2], sB[0][3]));
#pragma unroll
    for (int nk = 1; nk < 4; ++nk) {
      lmA = fmaxf(lmA, fmaxf(fmaxf(sA[nk][0], sA[nk][1]), fmaxf(sA[nk][2], sA[nk][3])));
      lmB = fmaxf(lmB, fmaxf(fmaxf(sB[nk][0], sB[nk][1]), fmaxf(sB[nk][2], sB[nk][3])));
    }
    lmA = fmaxf(lmA, __shfl_xor(lmA, 16));
    lmA = fmaxf(lmA, __shfl_xor(lmA, 32));
    lmB = fmaxf(lmB, __shfl_xor(lmB, 16));
    lmB = fmaxf(lmB, __shfl_xor(lmB, 32));
    lmA *= C1;
    lmB *= C1;

    if (__any((lmA > MA + THR) | (lmB > MB + THR))) {   // T13 defer-max (rare)
      const float mnA = fmaxf(MA, lmA);
      const float mnB = fmaxf(MB, lmB);
      const float aA = exp2g(MA - mnA);
      const float aB = exp2g(MB - mnB);
      MA = mnA; MB = mnB;
      osA[0] *= aA; osB[0] *= aB;
#pragma unroll
      for (int nd = 0; nd < 4; ++nd)
#pragma unroll
        for (int r = 0; r < 4; ++r) { oA[nd][r] *= aA; oB[nd][r] *= aB; }
    }

    // ---- exp2 in place ----
#pragma unroll
    for (int nk = 0; nk < 4; ++nk)
#pragma unroll
      for (int r = 0; r < 4; ++r) {
        sA[nk][r] = exp2g(fmaf(sA[nk][r], C1, -MA));
        sB[nk][r] = exp2g(fmaf(sB[nk][r], C1, -MB));
      }

    // ---- P_A, P_B -> LDS: cvt_pk pairs, 8x ds_write_b64 ----
#pragma unroll
    for (int nk = 0; nk < 4; ++nk) {
      u32 loA, hiA, loB, hiB;
      asm("v_cvt_pk_bf16_f32 %0, %1, %2" : "=v"(loA) : "v"(sA[nk][0]), "v"(sA[nk][1]));
      asm("v_cvt_pk_bf16_f32 %0, %1, %2" : "=v"(hiA) : "v"(sA[nk][2]), "v"(sA[nk][3]));
      asm("v_cvt_pk_bf16_f32 %0, %1, %2" : "=v"(loB) : "v"(sB[nk][0]), "v"(sB[nk][1]));
      asm("v_cvt_pk_bf16_f32 %0, %1, %2" : "=v"(hiB) : "v"(sB[nk][2]), "v"(sB[nk][3]));
      *(u32x2*)(PwA + li * 128 + ((nk * 32 + 8 * g) ^ pswz)) = (u32x2){loA, hiA};
      *(u32x2*)(PwB + li * 128 + ((nk * 32 + 8 * g) ^ pswz)) = (u32x2){loB, hiB};
    }
    asm volatile("s_waitcnt lgkmcnt(0)" ::: "memory");

    // ---- hoist V fragments once; both PV passes reuse (8 reads serve 20 MFMA) ----
    s16x8 vf[2][4];
#pragma unroll
    for (int ks = 0; ks < 2; ++ks)
#pragma unroll
      for (int nd = 0; nd < 4; ++nd) {
        const int d = nd * 16 + li;
        vf[ks][nd] = *(const s16x8*)((char*)Vt + d * 128 + ((ks * 64 + 16 * g) ^ (((d ^ (d >> 3)) & 7) << 4)));
      }

    __builtin_amdgcn_s_setprio(1);
#pragma unroll
    for (int ks = 0; ks < 2; ++ks) {
      const s16x8 pfA = *(const s16x8*)(PwA + li * 128 + ((ks * 64 + 16 * g) ^ pswz));
      const s16x8 pfB = *(const s16x8*)(PwB + li * 128 + ((ks * 64 + 16 * g) ^ pswz));
#pragma unroll
      for (int nd = 0; nd < 4; ++nd) {
        oA[nd] = __builtin_amdgcn_mfma_f32_16x16x32_bf16(vf[ks][nd], pfA, oA[nd], 0, 0, 0);
        oB[nd] = __builtin_amdgcn_mfma_f32_16x16x32_bf16(vf[ks][nd], pfB, oB[nd], 0, 0, 0);
      }
      osA = __builtin_amdgcn_mfma_f32_16x16x32_bf16(ones, pfA, osA, 0, 0, 0);
      osB = __builtin_amdgcn_mfma_f32_16x16x32_bf16(ones, pfB, osB, 0, 0, 0);
    }
    __builtin_amdgcn_s_setprio(0);

    __syncthreads();   // all waves done with Ks[buf], Vt; prefetch drained next iter
    buf ^= 1;
  }

  // ---- epilogue: both q-blocks ----
  const float invA = 1.0f / osA[0];
  const float invB = 1.0f / osB[0];
  const size_t rowA = baserow + qbase + li;
#pragma unroll
  for (int nd = 0; nd < 4; ++nd) {
    ushort4 stA, stB;
    stA.x = f2bf(oA[nd][0] * invA);
    stA.y = f2bf(oA[nd][1] * invA);
    stA.z = f2bf(oA[nd][2] * invA);
    stA.w = f2bf(oA[nd][3] * invA);
    stB.x = f2bf(oB[nd][0] * invB);
    stB.y = f2bf(oB[nd][1] * invB);
    stB.z = f2bf(oB[nd][2] * invB);
    stB.w = f2bf(oB[nd][3] * invB);
    *(ushort4*)(outp + rowA * 1024 + h * 64 + nd * 16 + 4 * g)        = stA;
    *(ushort4*)(outp + (rowA + 16) * 1024 + h * 64 + nd * 16 + 4 * g) = stB;
  }
}

// ---------------- launcher ----------------
extern "C" void kernel_launch(void* const* d_in, const int* in_sizes, int n_in,
                              void* d_out, int out_size, void* d_ws, size_t ws_size,
                              hipStream_t stream)
{
  const float* x     = (const float*)d_in[0];
  const float* gamma = (const float*)d_in[1];
  const float* beta  = (const float*)d_in[2];
  const float* Wqkv  = (const float*)d_in[3];
  const float* bqkv  = (const float*)d_in[4];
  const float* Wout  = (const float*)d_in[5];
  const float* bout  = (const float*)d_in[6];
  float* out = (float*)d_out;

  char* ws = (char*)d_ws;
  u16* xn     = (u16*)(ws);                       // 8 MB  [4096][1024]
  u16* wqkv_t = (u16*)(ws + ((size_t)8  << 20));  // 6 MB  [3072][1024]
  u16* wout_t = (u16*)(ws + ((size_t)14 << 20));  // 2 MB  [1024][1024]
  u16* qkv    = (u16*)(ws + ((size_t)16 << 20));  // 24 MB [4096][3072]
  u16* attn   = (u16*)(ws + ((size_t)40 << 20));  // 8 MB  [4096][1024]

  ln_kernel<<<4096, 256, 0, stream>>>(x, gamma, beta, xn);
  transpose_cvt<<<dim3(96, 32), dim3(32, 8), 0, stream>>>(Wqkv, wqkv_t, 1024, 3072);
  transpose_cvt<<<dim3(32, 32), dim3(32, 8), 0, stream>>>(Wout, wout_t, 1024, 1024);
  gemm_bt<u16><<<dim3(24, 32), 256, 0, stream>>>(xn, wqkv_t, bqkv, qkv, 4096, 3072, 1024);
  attn_kernel<<<512, 256, 0, stream>>>(qkv, attn);
  gemm_bt64<float><<<dim3(8, 64), 256, 0, stream>>>(attn, wout_t, bout, out, 4096, 1024, 1024);
}